// Round 3
// baseline (500.348 us; speedup 1.0000x reference)
//
#include <hip/hip_runtime.h>
#include <cstdint>

typedef __attribute__((ext_vector_type(8))) __bf16 bf16x8;
typedef __attribute__((ext_vector_type(4))) __bf16 bf16x4;
typedef __attribute__((ext_vector_type(4))) float f32x4;

#define MFMA16(a, b, c) __builtin_amdgcn_mfma_f32_16x16x32_bf16((a), (b), (c), 0, 0, 0)

static constexpr int SEQ = 2048;
static constexpr int DV = 256;
static constexpr float QK_SCALE = 4.5f;  // qk / INV_SCALE, INV_SCALE = 1/(0.5*9)

__device__ __forceinline__ bf16x4 cvt4(float4 v) {
    bf16x4 y;
    y[0] = (__bf16)v.x; y[1] = (__bf16)v.y; y[2] = (__bf16)v.z; y[3] = (__bf16)v.w;
    return y;
}

// ---------------------------------------------------------------------------
// Projection GEMM (unchanged — single barrier pair, ~2 us each)
// ---------------------------------------------------------------------------
template <int K, int TRANS>
__global__ __launch_bounds__(256) void k_proj(const float* __restrict__ X,
                                              const float* __restrict__ W,
                                              __bf16* __restrict__ out,
                                              float outScale) {
    __shared__ __bf16 ldsX[64][136];
    __shared__ __bf16 ldsW[128][136];

    const int t = threadIdx.x;
    const int m0 = blockIdx.x * 64;
    const int w = t >> 6, l = t & 63, lrow = l & 15, lq = l >> 4;

    f32x4 acc[8];
#pragma unroll
    for (int i = 0; i < 8; ++i) acc[i] = f32x4{0.f, 0.f, 0.f, 0.f};

#pragma unroll
    for (int kh = 0; kh < K / 128; ++kh) {
        if (kh) __syncthreads();
#pragma unroll
        for (int i = 0; i < 8; ++i) {
            int idx = t + i * 256;
            int r = idx >> 5, c4 = idx & 31;
            float4 v = *(const float4*)(X + (size_t)(m0 + r) * K + kh * 128 + c4 * 4);
            *(bf16x4*)&ldsX[r][c4 * 4] = cvt4(v);
        }
#pragma unroll
        for (int i = 0; i < 16; ++i) {
            int idx = t + i * 256;
            int r = idx >> 5, c4 = idx & 31;
            float4 v = *(const float4*)(W + (size_t)r * K + kh * 128 + c4 * 4);
            *(bf16x4*)&ldsW[r][c4 * 4] = cvt4(v);
        }
        __syncthreads();

        bf16x8 aA[4];
#pragma unroll
        for (int kc = 0; kc < 4; ++kc)
            aA[kc] = *(const bf16x8*)((const char*)&ldsX[w * 16 + lrow][0] + kc * 64 + lq * 16);
#pragma unroll
        for (int nt = 0; nt < 8; ++nt) {
#pragma unroll
            for (int kc = 0; kc < 4; ++kc) {
                bf16x8 bB = *(const bf16x8*)((const char*)&ldsW[nt * 16 + lrow][0] + kc * 64 + lq * 16);
                acc[nt] = MFMA16(aA[kc], bB, acc[nt]);
            }
        }
    }

#pragma unroll
    for (int nt = 0; nt < 8; ++nt) {
#pragma unroll
        for (int j = 0; j < 4; ++j) {
            int gm = m0 + w * 16 + lq * 4 + j;
            int col = nt * 16 + lrow;
            float v = acc[nt][j] * outScale;
            if (TRANS) {
                int b = gm >> 11, s = gm & 2047;
                out[((size_t)b * 128 + col) * SEQ + s] = (__bf16)v;
            } else {
                out[(size_t)gm * 128 + col] = (__bf16)v;
            }
        }
    }
}

// ---------------------------------------------------------------------------
// value [8][2048][256] fp32 -> vt [8][256][2048] bf16 (unchanged)
// ---------------------------------------------------------------------------
__global__ __launch_bounds__(256) void k_vt(const float* __restrict__ V, __bf16* __restrict__ vt) {
    __shared__ __bf16 tile[64][72];
    const int t = threadIdx.x;
    const int b = blockIdx.z, s0 = blockIdx.x * 64, v0 = blockIdx.y * 64;
#pragma unroll
    for (int i = 0; i < 4; ++i) {
        int idx = t + i * 256;
        int r = idx >> 4, c4 = idx & 15;
        float4 x = *(const float4*)(V + ((size_t)b * SEQ + s0 + r) * DV + v0 + c4 * 4);
        *(bf16x4*)&tile[r][c4 * 4] = cvt4(x);
    }
    __syncthreads();
#pragma unroll
    for (int i = 0; i < 4; ++i) {
        int idx = t + i * 256;
        int v = idx >> 4, c4 = idx & 15;
        bf16x4 y;
        y[0] = tile[c4 * 4 + 0][v]; y[1] = tile[c4 * 4 + 1][v];
        y[2] = tile[c4 * 4 + 2][v]; y[3] = tile[c4 * 4 + 3][v];
        *(bf16x4*)(vt + ((size_t)b * DV + v0 + v) * SEQ + s0 + c4 * 4) = y;
    }
}

__global__ __launch_bounds__(256) void k_cvt_bf16(const float* __restrict__ src,
                                                  __bf16* __restrict__ dst, int n4) {
    int i = blockIdx.x * 256 + threadIdx.x;
    if (i < n4) {
        float4 v = *(const float4*)(src + (size_t)i * 4);
        *(bf16x4*)(dst + (size_t)i * 4) = cvt4(v);
    }
}

// ---------------------------------------------------------------------------
// Flash attention v3: BARRIER-FREE. All B-fragments direct global->reg
// (per-lane contiguous 16B, L1/L2-served), register double-buffered one
// k-step ahead. Only wave-local lgkmcnt(0) for the P C->A round-trip.
// ---------------------------------------------------------------------------
__global__ __launch_bounds__(256, 1) void k_flash(const __bf16* __restrict__ r1s,
                                                  const __bf16* __restrict__ r2,
                                                  const __bf16* __restrict__ r3t,
                                                  __bf16* __restrict__ v1) {
    __shared__ __bf16 plds[4][16][48];  // per-wave P round-trip, 96B rows

    const int t = threadIdx.x, bx = blockIdx.x;
    const int b = bx >> 5, q0 = (bx & 31) * 64;
    const int w = t >> 6, l = t & 63, lrow = l & 15, lq = l >> 4;

    const __bf16* r1b = r1s + (size_t)b * SEQ * 128;
    const __bf16* r2b = r2 + (size_t)b * SEQ * 128;
    const __bf16* r3b = r3t + (size_t)b * 128 * SEQ;

    // resident A-fragments of r1 (16 q-rows per wave)
    bf16x8 aQ[4];
    {
        const __bf16* p = r1b + (size_t)(q0 + w * 16 + lrow) * 128 + lq * 8;
#pragma unroll
        for (int kc = 0; kc < 4; ++kc) aQ[kc] = *(const bf16x8*)(p + kc * 32);
    }

    // per-lane B-frag base pointers
    const __bf16* pK = r2b + (size_t)lrow * 128 + lq * 8;  // + (it*32+ct*16)*128 + kc*32
    const __bf16* pV = r3b + (size_t)lrow * SEQ + lq * 8;  // + ot*16*SEQ + it*32

    f32x4 acc[8];
#pragma unroll
    for (int i = 0; i < 8; ++i) acc[i] = f32x4{0.f, 0.f, 0.f, 0.f};
    float mrow[4] = {-INFINITY, -INFINITY, -INFINITY, -INFINITY};
    float lsum[4] = {0.f, 0.f, 0.f, 0.f};

    bf16x8 bK0[8], bV0[8], bK1[8], bV1[8];

    auto loadB = [&](bf16x8* bK, bf16x8* bV, int it) {
#pragma unroll
        for (int ct = 0; ct < 2; ++ct)
#pragma unroll
            for (int kc = 0; kc < 4; ++kc)
                bK[ct * 4 + kc] = *(const bf16x8*)(pK + (size_t)(it * 32 + ct * 16) * 128 + kc * 32);
#pragma unroll
        for (int ot = 0; ot < 8; ++ot)
            bV[ot] = *(const bf16x8*)(pV + (size_t)ot * 16 * SEQ + it * 32);
    };

    auto step = [&](const bf16x8* bK, const bf16x8* bV) {
        // S = r1 . r2^T (16q x 32k)
        f32x4 sc[2];
#pragma unroll
        for (int ct = 0; ct < 2; ++ct) {
            f32x4 s = f32x4{0.f, 0.f, 0.f, 0.f};
#pragma unroll
            for (int kc = 0; kc < 4; ++kc) s = MFMA16(aQ[kc], bK[ct * 4 + kc], s);
            sc[ct] = s;
        }
        // online softmax (rows live across lanes sharing lq)
        float pm[4], ps[4], al[4];
#pragma unroll
        for (int j = 0; j < 4; ++j) pm[j] = fmaxf(sc[0][j], sc[1][j]);
#pragma unroll
        for (int off = 1; off <= 8; off <<= 1)
#pragma unroll
            for (int j = 0; j < 4; ++j) pm[j] = fmaxf(pm[j], __shfl_xor(pm[j], off, 64));
#pragma unroll
        for (int j = 0; j < 4; ++j) {
            float mn = fmaxf(mrow[j], pm[j]);
            al[j] = __expf(mrow[j] - mn);
            mrow[j] = mn;
            ps[j] = 0.f;
        }
        float pr[2][4];
#pragma unroll
        for (int ct = 0; ct < 2; ++ct)
#pragma unroll
            for (int j = 0; j < 4; ++j) {
                float p = __expf(sc[ct][j] - mrow[j]);
                pr[ct][j] = p;
                ps[j] += p;
            }
#pragma unroll
        for (int off = 1; off <= 8; off <<= 1)
#pragma unroll
            for (int j = 0; j < 4; ++j) ps[j] += __shfl_xor(ps[j], off, 64);
#pragma unroll
        for (int j = 0; j < 4; ++j) lsum[j] = lsum[j] * al[j] + ps[j];
#pragma unroll
        for (int ot = 0; ot < 8; ++ot)
#pragma unroll
            for (int j = 0; j < 4; ++j) acc[ot][j] *= al[j];
        // P: C-layout -> LDS -> A-layout (wave-local, lgkmcnt only)
#pragma unroll
        for (int ct = 0; ct < 2; ++ct)
#pragma unroll
            for (int j = 0; j < 4; ++j)
                plds[w][lq * 4 + j][ct * 16 + lrow] = (__bf16)pr[ct][j];
        __builtin_amdgcn_s_waitcnt(0xc07f);  // lgkmcnt(0), keep VMEM in flight
        bf16x8 pA = *(const bf16x8*)&plds[w][lrow][lq * 8];
#pragma unroll
        for (int ot = 0; ot < 8; ++ot) acc[ot] = MFMA16(pA, bV[ot], acc[ot]);
    };

    loadB(bK0, bV0, 0);
    for (int it2 = 0; it2 < 32; ++it2) {
        const int it = it2 * 2;
        loadB(bK1, bV1, it + 1);
        step(bK0, bV0);
        if (it + 2 < 64) loadB(bK0, bV0, it + 2);
        step(bK1, bV1);
    }

#pragma unroll
    for (int ot = 0; ot < 8; ++ot)
#pragma unroll
        for (int j = 0; j < 4; ++j) {
            int q = q0 + w * 16 + lq * 4 + j;
            float v = acc[ot][j] / lsum[j];
            v1[((size_t)b * SEQ + q) * 128 + ot * 16 + lrow] = (__bf16)v;
        }
}

// ---------------------------------------------------------------------------
// out = mask@value + (P@r3)@Wout^T.  v3: BARRIER-FREE, zero LDS. mask A-frags
// (2x float4/lane, HBM) and vt B-frags (8x 16B/lane, L1/L2) direct to regs,
// register double-buffered. 32 q-rows/wg, grid 512.
// ---------------------------------------------------------------------------
__global__ __launch_bounds__(256, 2) void k_out(const float* __restrict__ mask,
                                                const __bf16* __restrict__ vtb,
                                                const __bf16* __restrict__ v1,
                                                const __bf16* __restrict__ wob,
                                                float* __restrict__ out) {
    const int t = threadIdx.x;
    const int m0 = blockIdx.x * 32;
    const int b = m0 >> 11, q0 = m0 & 2047;
    const int w = t >> 6, l = t & 63, lrow = l & 15, lq = l >> 4;
    const int rg = w & 1, ch = w >> 1;  // 16-row group x 128-col half

    f32x4 acc[8];
#pragma unroll
    for (int i = 0; i < 8; ++i) acc[i] = f32x4{0.f, 0.f, 0.f, 0.f};

    const float* pM = mask + ((size_t)b * SEQ + q0 + rg * 16 + lrow) * SEQ + lq * 8;
    const __bf16* pV = vtb + ((size_t)b * DV + ch * 128 + lrow) * SEQ + lq * 8;

    float4 mA0[2], mA1[2];
    bf16x8 vB0[8], vB1[8];

    auto loadIt = [&](float4* mA, bf16x8* vB, int it) {
        mA[0] = *(const float4*)(pM + it * 32);
        mA[1] = *(const float4*)(pM + it * 32 + 4);
#pragma unroll
        for (int vt8 = 0; vt8 < 8; ++vt8)
            vB[vt8] = *(const bf16x8*)(pV + (size_t)vt8 * 16 * SEQ + it * 32);
    };

    auto step = [&](const float4* mA, const bf16x8* vB) {
        bf16x8 aM;
        aM[0] = (__bf16)mA[0].x; aM[1] = (__bf16)mA[0].y; aM[2] = (__bf16)mA[0].z; aM[3] = (__bf16)mA[0].w;
        aM[4] = (__bf16)mA[1].x; aM[5] = (__bf16)mA[1].y; aM[6] = (__bf16)mA[1].z; aM[7] = (__bf16)mA[1].w;
#pragma unroll
        for (int vt8 = 0; vt8 < 8; ++vt8) acc[vt8] = MFMA16(aM, vB[vt8], acc[vt8]);
    };

    loadIt(mA0, vB0, 0);
    for (int it2 = 0; it2 < 32; ++it2) {
        const int it = it2 * 2;
        loadIt(mA1, vB1, it + 1);
        step(mA0, vB0);
        if (it + 2 < 64) loadIt(mA0, vB0, it + 2);
        step(mA1, vB1);
    }

    // epilogue: + v1 @ Wout^T (small, L2-hot)
    bf16x8 aV[4];
#pragma unroll
    for (int oc = 0; oc < 4; ++oc)
        aV[oc] = *(const bf16x8*)(v1 + (size_t)(m0 + rg * 16 + lrow) * 128 + oc * 32 + lq * 8);
#pragma unroll
    for (int vt8 = 0; vt8 < 8; ++vt8) {
#pragma unroll
        for (int oc = 0; oc < 4; ++oc) {
            bf16x8 bb = *(const bf16x8*)(wob + (size_t)(ch * 128 + vt8 * 16 + lrow) * 128 + oc * 32 + lq * 8);
            acc[vt8] = MFMA16(aV[oc], bb, acc[vt8]);
        }
    }

#pragma unroll
    for (int vt8 = 0; vt8 < 8; ++vt8)
#pragma unroll
        for (int j = 0; j < 4; ++j) {
            int gq = m0 + rg * 16 + lq * 4 + j;
            out[(size_t)gq * 256 + ch * 128 + vt8 * 16 + lrow] = acc[vt8][j];
        }
}

// ---------------------------------------------------------------------------
extern "C" void kernel_launch(void* const* d_in, const int* in_sizes, int n_in,
                              void* d_out, int out_size, void* d_ws, size_t ws_size,
                              hipStream_t stream) {
    const float* q    = (const float*)d_in[0];
    const float* k    = (const float*)d_in[1];
    const float* v    = (const float*)d_in[2];
    const float* mask = (const float*)d_in[3];
    const float* W0   = (const float*)d_in[4];
    const float* W1   = (const float*)d_in[5];
    const float* W2   = (const float*)d_in[6];
    const float* Wout = (const float*)d_in[7];
    float* out = (float*)d_out;

    char* ws = (char*)d_ws;
    __bf16* r1s = (__bf16*)(ws);                  // [8][2048][128] bf16 (pre-scaled 4.5)
    __bf16* r2b = (__bf16*)(ws + (4ull << 20));   // [8][2048][128] bf16
    __bf16* r3t = (__bf16*)(ws + (8ull << 20));   // [8][128][2048] bf16 (transposed)
    __bf16* vtb = (__bf16*)(ws + (12ull << 20));  // [8][256][2048] bf16 (transposed)
    __bf16* wob = (__bf16*)(ws + (20ull << 20));  // [256][128] bf16
    __bf16* v1b = (__bf16*)(ws + (21ull << 20));  // [8][2048][128] bf16

    k_proj<128, 0><<<256, 256, 0, stream>>>(q, W0, r1s, QK_SCALE);
    k_proj<128, 0><<<256, 256, 0, stream>>>(k, W1, r2b, 1.0f);
    k_proj<256, 1><<<256, 256, 0, stream>>>(v, W2, r3t, 1.0f);
    k_vt<<<dim3(32, 4, 8), 256, 0, stream>>>(v, vtb);
    k_cvt_bf16<<<32, 256, 0, stream>>>(Wout, wob, 8192);
    k_flash<<<256, 256, 0, stream>>>(r1s, r2b, r3t, v1b);
    k_out<<<512, 256, 0, stream>>>(mask, vtb, v1b, wob, out);
}